// Round 1
// 240.336 us; speedup vs baseline: 1.0336x; 1.0336x over previous
//
#include <hip/hip_runtime.h>
#include <hip/hip_bf16.h>

// SupplyChainGNN: 3-layer GCN, N=50000, E=800000, H=64.
// Round 12: fuse gather+conv per layer (gconv / gconv_heads). Gathered rows
// go half-wave-registers -> LDS (feature-major, stride 65: free banks both
// directions) -> conv reads LDS, writes bf16 hn directly. Removes the g
// 25.6MB/layer round trip, 3 dispatches, and overlaps conv VALU with other
// blocks' scattered gather loads. Gather inner loop unchanged from R10 (it
// sits at the measured scattered-access ceiling ~12-13 line-req/ns).

#define HDIM 64
#define PB 128          // blocks in hist/bin passes
#define NPB 256         // nodes per bucket
#define NPB_SHIFT 8

__device__ inline unsigned bfpack(float lo, float hi) {
    unsigned ul = __float_as_uint(lo), uh = __float_as_uint(hi);
    ul += 0x7fffu + ((ul >> 16) & 1u);
    uh += 0x7fffu + ((uh >> 16) & 1u);
    return (ul >> 16) | (uh & 0xffff0000u);
}

__device__ inline float2 bfunpack(unsigned u) {
    float2 r;
    r.x = __uint_as_float(u << 16);
    r.y = __uint_as_float(u & 0xffff0000u);
    return r;
}

// Pass 1: histT[k*PB + p] = #edges of block p with dst in bucket k  (NB<=256)
__global__ __launch_bounds__(256) void hist_pass(const int* __restrict__ dst,
                                                 unsigned* __restrict__ histT,
                                                 int E, int NB) {
    __shared__ unsigned h[256];
    int t = threadIdx.x, p = blockIdx.x;
    h[t] = 0u;
    __syncthreads();
    int chunk = (E + PB - 1) / PB;
    int lo = p * chunk, hi = min(lo + chunk, E);
    for (int e = lo + t; e < hi; e += 256)
        atomicAdd(&h[dst[e] >> NPB_SHIFT], 1u);
    __syncthreads();
    if (t < NB) histT[t * PB + p] = h[t];
}

// Pass 2: per-bucket exclusive scan of its PB per-block counts (in place);
// bucket total -> btot[k].
__global__ __launch_bounds__(128) void scan_bucket(unsigned* __restrict__ histT,
                                                   unsigned* __restrict__ btot) {
    __shared__ unsigned s[PB];
    int t = threadIdx.x, k = blockIdx.x;
    unsigned v = histT[k * PB + t];
    s[t] = v;
    __syncthreads();
#pragma unroll
    for (int off = 1; off < PB; off <<= 1) {
        unsigned u = (t >= off) ? s[t - off] : 0u;
        __syncthreads();
        s[t] += u;
        __syncthreads();
    }
    histT[k * PB + t] = s[t] - v;
    if (t == PB - 1) btot[k] = s[t];
}

// Pass 3: scatter packed (dst_local<<16)|src into bucket-grouped ebuf.
__global__ __launch_bounds__(256) void bin_pass(const int* __restrict__ ei,
                                                const unsigned* __restrict__ histT,
                                                const unsigned* __restrict__ btot,
                                                unsigned* __restrict__ ebuf,
                                                int E, int NB) {
    __shared__ unsigned bb[256];
    __shared__ unsigned cur[256];
    int t = threadIdx.x, p = blockIdx.x;
    unsigned bv = (t < NB) ? btot[t] : 0u;
    bb[t] = bv;
    __syncthreads();
#pragma unroll
    for (int off = 1; off < 256; off <<= 1) {
        unsigned u = (t >= off) ? bb[t - off] : 0u;
        __syncthreads();
        bb[t] += u;
        __syncthreads();
    }
    if (t < NB) cur[t] = histT[t * PB + p] + (bb[t] - bv);
    __syncthreads();
    int chunk = (E + PB - 1) / PB;
    int lo = p * chunk, hi = min(lo + chunk, E);
    for (int e = lo + t; e < hi; e += 256) {
        unsigned sN = (unsigned)ei[e];
        unsigned dN = (unsigned)ei[E + e];
        unsigned pos = atomicAdd(&cur[dN >> NPB_SHIFT], 1u);
        ebuf[pos] = ((dN & (NPB - 1u)) << 16) | sN;
    }
}

// Pass 4: one block per bucket -> row_ptr, dinv, csr_src.
__global__ __launch_bounds__(256) void csr_pass(const unsigned* __restrict__ ebuf,
                                                const unsigned* __restrict__ btot,
                                                unsigned* __restrict__ row_ptr,
                                                float* __restrict__ dinv,
                                                int* __restrict__ csr_src,
                                                int N, int E, int NB) {
    __shared__ unsigned bb[256];
    __shared__ unsigned cntL[NPB];
    __shared__ unsigned sc[NPB];
    __shared__ unsigned cur[NPB];
    int t = threadIdx.x, k = blockIdx.x;
    unsigned bv = (t < NB) ? btot[t] : 0u;
    bb[t] = bv;
    __syncthreads();
#pragma unroll
    for (int off = 1; off < 256; off <<= 1) {
        unsigned u = (t >= off) ? bb[t - off] : 0u;
        __syncthreads();
        bb[t] += u;
        __syncthreads();
    }
    unsigned e1 = bb[k];
    unsigned e0 = e1 - btot[k];
    int nbase = k << NPB_SHIFT;
    cntL[t] = 0u;
    __syncthreads();
    for (unsigned e = e0 + t; e < e1; e += 256)
        atomicAdd(&cntL[ebuf[e] >> 16], 1u);
    __syncthreads();
    unsigned v = cntL[t];
    sc[t] = v;
    __syncthreads();
#pragma unroll
    for (int off = 1; off < NPB; off <<= 1) {
        unsigned u = (t >= off) ? sc[t - off] : 0u;
        __syncthreads();
        sc[t] += u;
        __syncthreads();
    }
    unsigned pos0 = e0 + sc[t] - v;
    cur[t] = pos0;
    int node = nbase + t;
    if (node < N) {
        row_ptr[node] = pos0;
        dinv[node] = rsqrtf((float)(v + 1u));
    }
    if (k == NB - 1 && t == 0) row_ptr[N] = (unsigned)E;
    __syncthreads();
    for (unsigned e = e0 + t; e < e1; e += 256) {
        unsigned ed = ebuf[e];
        unsigned pos = atomicAdd(&cur[ed >> 16], 1u);
        csr_src[pos] = (int)(ed & 0xffffu);
    }
}

// hn[i] = bf16( dinv[i] * relu(x@W+b) ); thread per feature-pair.
__global__ __launch_bounds__(256) void encoder(const float* __restrict__ x,
                                               const float* __restrict__ W,
                                               const float* __restrict__ b,
                                               const float* __restrict__ dinv,
                                               unsigned* __restrict__ hn, int N) {
    int t = blockIdx.x * 256 + threadIdx.x;
    int i = t >> 5, jp = t & 31;
    if (i >= N) return;
    int j0 = 2 * jp;
    float a0 = b[j0], a1 = b[j0 + 1];
#pragma unroll
    for (int k = 0; k < 5; k++) {
        float xv = x[i * 5 + k];
        a0 = fmaf(xv, W[k * 64 + j0], a0);
        a1 = fmaf(xv, W[k * 64 + j0 + 1], a1);
    }
    float di = dinv[i];
    hn[t] = bfpack(di * fmaxf(a0, 0.0f), di * fmaxf(a1, 0.0f));
}

// Per-node gather (half-wave, 32 lanes, lane fl owns features 2fl,2fl+1).
// Software-pipelined 8-deep — unchanged from R10 (at scattered-request ceiling).
__device__ inline float2 gather_row(const unsigned* __restrict__ row_ptr,
                                    const int* __restrict__ csr_src,
                                    const unsigned* __restrict__ hn,
                                    int i, int fl) {
    float2 a0 = bfunpack(hn[(size_t)i * 32 + fl]);  // self term
    float2 a1 = {0.f, 0.f}, a2 = {0.f, 0.f}, a3 = {0.f, 0.f};
    float2 a4 = {0.f, 0.f}, a5 = {0.f, 0.f}, a6 = {0.f, 0.f}, a7 = {0.f, 0.f};
    unsigned e0 = row_ptr[i];
    unsigned cnt = row_ptr[i + 1] - e0;
    const int* idx = csr_src + e0;
    unsigned u = 0;
    if (cnt >= 8) {
        int s0 = idx[0], s1 = idx[1], s2 = idx[2], s3 = idx[3];
        int s4 = idx[4], s5 = idx[5], s6 = idx[6], s7 = idx[7];
        while (true) {
            unsigned v0 = hn[(size_t)s0 * 32 + fl];
            unsigned v1 = hn[(size_t)s1 * 32 + fl];
            unsigned v2 = hn[(size_t)s2 * 32 + fl];
            unsigned v3 = hn[(size_t)s3 * 32 + fl];
            unsigned v4 = hn[(size_t)s4 * 32 + fl];
            unsigned v5 = hn[(size_t)s5 * 32 + fl];
            unsigned v6 = hn[(size_t)s6 * 32 + fl];
            unsigned v7 = hn[(size_t)s7 * 32 + fl];
            unsigned un = u + 8;
            bool more = (un + 8 <= cnt);
            if (more) {
                s0 = idx[un + 0]; s1 = idx[un + 1]; s2 = idx[un + 2]; s3 = idx[un + 3];
                s4 = idx[un + 4]; s5 = idx[un + 5]; s6 = idx[un + 6]; s7 = idx[un + 7];
            }
            float2 f0 = bfunpack(v0), f1 = bfunpack(v1), f2 = bfunpack(v2), f3 = bfunpack(v3);
            float2 f4 = bfunpack(v4), f5 = bfunpack(v5), f6 = bfunpack(v6), f7 = bfunpack(v7);
            a0.x += f0.x; a0.y += f0.y;  a1.x += f1.x; a1.y += f1.y;
            a2.x += f2.x; a2.y += f2.y;  a3.x += f3.x; a3.y += f3.y;
            a4.x += f4.x; a4.y += f4.y;  a5.x += f5.x; a5.y += f5.y;
            a6.x += f6.x; a6.y += f6.y;  a7.x += f7.x; a7.y += f7.y;
            u = un;
            if (!more) break;
        }
    }
    if (u < cnt) {  // predicated parallel remainder (1..7 edges)
        unsigned last = cnt - 1;
        int s0 = idx[u];
        int s1 = idx[min(u + 1, last)];
        int s2 = idx[min(u + 2, last)];
        int s3 = idx[min(u + 3, last)];
        int s4 = idx[min(u + 4, last)];
        int s5 = idx[min(u + 5, last)];
        int s6 = idx[min(u + 6, last)];
        int s7 = idx[min(u + 7, last)];
        unsigned v0 = hn[(size_t)s0 * 32 + fl];
        unsigned v1 = hn[(size_t)s1 * 32 + fl];
        unsigned v2 = hn[(size_t)s2 * 32 + fl];
        unsigned v3 = hn[(size_t)s3 * 32 + fl];
        unsigned v4 = hn[(size_t)s4 * 32 + fl];
        unsigned v5 = hn[(size_t)s5 * 32 + fl];
        unsigned v6 = hn[(size_t)s6 * 32 + fl];
        unsigned v7 = hn[(size_t)s7 * 32 + fl];
        float2 f0 = bfunpack(v0), f1 = bfunpack(v1), f2 = bfunpack(v2), f3 = bfunpack(v3);
        float2 f4 = bfunpack(v4), f5 = bfunpack(v5), f6 = bfunpack(v6), f7 = bfunpack(v7);
        a0.x += f0.x;                        a0.y += f0.y;
        a1.x += (u + 1 < cnt) ? f1.x : 0.f;  a1.y += (u + 1 < cnt) ? f1.y : 0.f;
        a2.x += (u + 2 < cnt) ? f2.x : 0.f;  a2.y += (u + 2 < cnt) ? f2.y : 0.f;
        a3.x += (u + 3 < cnt) ? f3.x : 0.f;  a3.y += (u + 3 < cnt) ? f3.y : 0.f;
        a4.x += (u + 4 < cnt) ? f4.x : 0.f;  a4.y += (u + 4 < cnt) ? f4.y : 0.f;
        a5.x += (u + 5 < cnt) ? f5.x : 0.f;  a5.y += (u + 5 < cnt) ? f5.y : 0.f;
        a6.x += (u + 6 < cnt) ? f6.x : 0.f;  a6.y += (u + 6 < cnt) ? f6.y : 0.f;
        a7.x += (u + 7 < cnt) ? f7.x : 0.f;  a7.y += (u + 7 < cnt) ? f7.y : 0.f;
    }
    a0.x += a1.x; a0.y += a1.y;  a2.x += a3.x; a2.y += a3.y;
    a4.x += a5.x; a4.y += a5.y;  a6.x += a7.x; a6.y += a7.y;
    a0.x += a2.x; a0.y += a2.y;  a4.x += a6.x; a4.y += a6.y;
    a0.x += a4.x; a0.y += a4.y;
    return a0;
}

// 16 FMAs: acc(float4) += h[4q..4q+3] * 4 columns of WT (stride 68, 16B aligned)
#define CONV_Q(ACC, W0, H, Q) do {                                              \
    float4 wa = *(const float4*)((W0) + 0 * 68 + 4 * (Q));                      \
    float4 wb = *(const float4*)((W0) + 1 * 68 + 4 * (Q));                      \
    float4 wc = *(const float4*)((W0) + 2 * 68 + 4 * (Q));                      \
    float4 wd = *(const float4*)((W0) + 3 * 68 + 4 * (Q));                      \
    ACC.x = fmaf(H[4*(Q)+0], wa.x, ACC.x); ACC.x = fmaf(H[4*(Q)+1], wa.y, ACC.x); \
    ACC.x = fmaf(H[4*(Q)+2], wa.z, ACC.x); ACC.x = fmaf(H[4*(Q)+3], wa.w, ACC.x); \
    ACC.y = fmaf(H[4*(Q)+0], wb.x, ACC.y); ACC.y = fmaf(H[4*(Q)+1], wb.y, ACC.y); \
    ACC.y = fmaf(H[4*(Q)+2], wb.z, ACC.y); ACC.y = fmaf(H[4*(Q)+3], wb.w, ACC.y); \
    ACC.z = fmaf(H[4*(Q)+0], wc.x, ACC.z); ACC.z = fmaf(H[4*(Q)+1], wc.y, ACC.z); \
    ACC.z = fmaf(H[4*(Q)+2], wc.z, ACC.z); ACC.z = fmaf(H[4*(Q)+3], wc.w, ACC.z); \
    ACC.w = fmaf(H[4*(Q)+0], wd.x, ACC.w); ACC.w = fmaf(H[4*(Q)+1], wd.y, ACC.w); \
    ACC.w = fmaf(H[4*(Q)+2], wd.z, ACC.w); ACC.w = fmaf(H[4*(Q)+3], wd.w, ACC.w); \
} while (0)

// Fused gather+conv, 64 nodes/block. Gather: 8 half-waves x 8 nodes serial,
// rows staged feature-major in LDS (stride 65: writes 2-way aliased = free,
// reads stride-1 = free). Conv: thread per (node, 16-output group); writes
// bf16 hn_out = dinv*relu(dinv*(row@W)+b) directly.
__global__ __launch_bounds__(256, 4) void gconv(const unsigned* __restrict__ row_ptr,
                                                const int* __restrict__ csr_src,
                                                const unsigned* __restrict__ hn_in,
                                                const float* __restrict__ W,
                                                const float* __restrict__ b,
                                                const float* __restrict__ dinv,
                                                unsigned* __restrict__ hn_out, int N) {
    __shared__ float WT[64 * 68];
    __shared__ float ybuf[64 * 65];   // [feature][node]
    int tid = threadIdx.x;
    for (int e = tid; e < 4096; e += 256) {
        int k = e >> 6, j = e & 63;
        WT[j * 68 + k] = W[e];
    }
    int hw = tid >> 5, fl = tid & 31;
    int base = blockIdx.x * 64;
    for (int s = 0; s < 8; s++) {
        int n = hw * 8 + s;
        int i = base + n;
        if (i < N) {
            float2 a = gather_row(row_ptr, csr_src, hn_in, i, fl);
            ybuf[(2 * fl) * 65 + n] = a.x;
            ybuf[(2 * fl + 1) * 65 + n] = a.y;
        }
    }
    __syncthreads();
    int n = tid & 63, qt = tid >> 6;
    int i = base + n;
    if (i >= N) return;
    float h[64];
#pragma unroll
    for (int k = 0; k < 64; k++) h[k] = ybuf[k * 65 + n];
    float di = dinv[i];
    int jb = qt * 16;
    unsigned pk[8];
#pragma unroll
    for (int j0 = 0; j0 < 16; j0 += 4) {
        float4 acc = {0.f, 0.f, 0.f, 0.f};
        const float* w0 = &WT[(jb + j0) * 68];
#pragma unroll
        for (int q = 0; q < 16; q++) CONV_Q(acc, w0, h, q);
        float4 y;
        y.x = fmaxf(fmaf(di, acc.x, b[jb + j0 + 0]), 0.f) * di;
        y.y = fmaxf(fmaf(di, acc.y, b[jb + j0 + 1]), 0.f) * di;
        y.z = fmaxf(fmaf(di, acc.z, b[jb + j0 + 2]), 0.f) * di;
        y.w = fmaxf(fmaf(di, acc.w, b[jb + j0 + 3]), 0.f) * di;
        pk[(j0 >> 1) + 0] = bfpack(y.x, y.y);
        pk[(j0 >> 1) + 1] = bfpack(y.z, y.w);
    }
    uint4* dst = (uint4*)(hn_out + (size_t)i * 32 + qt * 8);
    dst[0] = make_uint4(pk[0], pk[1], pk[2], pk[3]);
    dst[1] = make_uint4(pk[4], pk[5], pk[6], pk[7]);
}

// Layer 2: fused gather + conv + both MLP heads -> out.
__global__ __launch_bounds__(256, 4) void gconv_heads(const unsigned* __restrict__ row_ptr,
                                                      const int* __restrict__ csr_src,
                                                      const unsigned* __restrict__ hn_in,
                                                      const float* __restrict__ W,
                                                      const float* __restrict__ b,
                                                      const float* __restrict__ dinv,
                                                      const float* __restrict__ W_d1, const float* __restrict__ b_d1,
                                                      const float* __restrict__ W_d2, const float* __restrict__ b_d2,
                                                      const float* __restrict__ W_i1, const float* __restrict__ b_i1,
                                                      const float* __restrict__ W_i2, const float* __restrict__ b_i2,
                                                      float* __restrict__ out, int N) {
    __shared__ float WT[64 * 68];     // conv W^T, later 2x heads W1^T (2x 32x68 = 4352)
    __shared__ float ybuf[64 * 65];   // gathered rows, later y rows (feature-major)
    __shared__ float opart[256];
    int tid = threadIdx.x;
    for (int e = tid; e < 4096; e += 256) {
        int k = e >> 6, j = e & 63;
        WT[j * 68 + k] = W[e];
    }
    int hw = tid >> 5, fl = tid & 31;
    int base = blockIdx.x * 64;
    for (int s = 0; s < 8; s++) {
        int n = hw * 8 + s;
        int i = base + n;
        if (i < N) {
            float2 a = gather_row(row_ptr, csr_src, hn_in, i, fl);
            ybuf[(2 * fl) * 65 + n] = a.x;
            ybuf[(2 * fl + 1) * 65 + n] = a.y;
        }
    }
    __syncthreads();
    int n = tid & 63, qt = tid >> 6;
    int i = base + n;
    int jb = qt * 16;
    float y[16];
    if (i < N) {
        float h[64];
#pragma unroll
        for (int k = 0; k < 64; k++) h[k] = ybuf[k * 65 + n];
        float di = dinv[i];
#pragma unroll
        for (int j0 = 0; j0 < 16; j0 += 4) {
            float4 acc = {0.f, 0.f, 0.f, 0.f};
            const float* w0 = &WT[(jb + j0) * 68];
#pragma unroll
            for (int q = 0; q < 16; q++) CONV_Q(acc, w0, h, q);
            y[j0 + 0] = fmaxf(fmaf(di, acc.x, b[jb + j0 + 0]), 0.f);
            y[j0 + 1] = fmaxf(fmaf(di, acc.y, b[jb + j0 + 1]), 0.f);
            y[j0 + 2] = fmaxf(fmaf(di, acc.z, b[jb + j0 + 2]), 0.f);
            y[j0 + 3] = fmaxf(fmaf(di, acc.w, b[jb + j0 + 3]), 0.f);
        }
    }
    __syncthreads();   // all conv reads of WT/ybuf done
    if (i < N) {
#pragma unroll
        for (int jj = 0; jj < 16; jj++) ybuf[(jb + jj) * 65 + n] = y[jj];
    }
    for (int e = tid; e < 2048; e += 256) {   // reload WT with heads W1^T
        int k = e >> 5, j = e & 31;
        WT[j * 68 + k] = W_d1[e];
        WT[2176 + j * 68 + k] = W_i1[e];
    }
    __syncthreads();
    int head = qt >> 1, jh = qt & 1;
    float op = 0.f;
    if (i < N) {
        float hr[64];
#pragma unroll
        for (int k = 0; k < 64; k++) hr[k] = ybuf[k * 65 + n];
        const float* W1T = &WT[head * 2176];
        const float* b1 = head ? b_i1 : b_d1;
        const float* W2 = head ? W_i2 : W_d2;
        int hb = jh * 16;
#pragma unroll
        for (int j0 = 0; j0 < 16; j0 += 4) {
            float4 acc = {b1[hb + j0 + 0], b1[hb + j0 + 1], b1[hb + j0 + 2], b1[hb + j0 + 3]};
            const float* w0 = &W1T[(hb + j0) * 68];
#pragma unroll
            for (int q = 0; q < 16; q++) CONV_Q(acc, w0, hr, q);
            op = fmaf(fmaxf(acc.x, 0.f), W2[hb + j0 + 0], op);
            op = fmaf(fmaxf(acc.y, 0.f), W2[hb + j0 + 1], op);
            op = fmaf(fmaxf(acc.z, 0.f), W2[hb + j0 + 2], op);
            op = fmaf(fmaxf(acc.w, 0.f), W2[hb + j0 + 3], op);
        }
    }
    opart[qt * 64 + n] = op;
    __syncthreads();
    if (tid < 128) {
        int n2 = tid & 63, hd = tid >> 6;
        int i2 = base + n2;
        if (i2 < N) {
            float o = opart[hd * 128 + n2] + opart[hd * 128 + 64 + n2]
                    + (hd ? b_i2[0] : b_d2[0]);
            out[(size_t)hd * N + i2] = o;
        }
    }
}

extern "C" void kernel_launch(void* const* d_in, const int* in_sizes, int n_in,
                              void* d_out, int out_size, void* d_ws, size_t ws_size,
                              hipStream_t stream) {
    const float* x      = (const float*)d_in[0];
    const int*   ei     = (const int*)d_in[1];
    const float* W_enc  = (const float*)d_in[2];
    const float* b_enc  = (const float*)d_in[3];
    const float* conv_W = (const float*)d_in[4];
    const float* conv_b = (const float*)d_in[5];
    const float* W_d1   = (const float*)d_in[6];
    const float* b_d1   = (const float*)d_in[7];
    const float* W_d2   = (const float*)d_in[8];
    const float* b_d2   = (const float*)d_in[9];
    const float* W_i1   = (const float*)d_in[10];
    const float* b_i1   = (const float*)d_in[11];
    const float* W_i2   = (const float*)d_in[12];
    const float* b_i2   = (const float*)d_in[13];

    const int N = in_sizes[0] / 5;
    const int E = in_sizes[1] / 2;
    const int NB = (N + NPB - 1) >> NPB_SHIFT;   // <= 256

    // Workspace layout (same offsets as R11; hnA aliases ebuf — ebuf is dead
    // after csr_pass, before encoder writes hnA).
    float* g    = (float*)d_ws;                           // [N*64] region
    unsigned* hnA = (unsigned*)d_ws;                      // [N*32] bf16x2
    unsigned* hnB = (unsigned*)(g + (size_t)N * HDIM);    // [N*32] bf16x2 (old hbf)
    float* dinv = (float*)(hnB + (size_t)N * 32);
    unsigned* row_ptr = (unsigned*)(dinv + N);            // [N+1]
    unsigned* histT   = row_ptr + N + 1;                  // [NB*PB]
    unsigned* btot    = histT + (size_t)NB * PB;          // [NB]
    int* csr_src      = (int*)(btot + NB);                // [E]
    unsigned* ebuf    = (unsigned*)d_ws;                  // [E] packed (dead before encoder)
    float* out = (float*)d_out;

    const int gBlocks = (N + 63) / 64;   // 64 nodes per fused block

    // CSR build: bucket sort, no global atomics
    hist_pass<<<PB, 256, 0, stream>>>(ei + E, histT, E, NB);
    scan_bucket<<<NB, 128, 0, stream>>>(histT, btot);
    bin_pass<<<PB, 256, 0, stream>>>(ei, histT, btot, ebuf, E, NB);
    csr_pass<<<NB, 256, 0, stream>>>(ebuf, btot, row_ptr, dinv, csr_src, N, E, NB);

    // encoder -> hnA (bf16, dinv-prescaled)
    encoder<<<(N * 32 + 255) / 256, 256, 0, stream>>>(x, W_enc, b_enc, dinv, hnA, N);

    // fused gather+conv per layer (ping-pong hnA/hnB), layer 2 fused with heads
    gconv<<<gBlocks, 256, 0, stream>>>(row_ptr, csr_src, hnA,
                                       conv_W + 0 * HDIM * HDIM, conv_b + 0 * HDIM,
                                       dinv, hnB, N);
    gconv<<<gBlocks, 256, 0, stream>>>(row_ptr, csr_src, hnB,
                                       conv_W + 1 * HDIM * HDIM, conv_b + 1 * HDIM,
                                       dinv, hnA, N);
    gconv_heads<<<gBlocks, 256, 0, stream>>>(row_ptr, csr_src, hnA,
                                             conv_W + 2 * HDIM * HDIM, conv_b + 2 * HDIM,
                                             dinv, W_d1, b_d1, W_d2, b_d2,
                                             W_i1, b_i1, W_i2, b_i2, out, N);
}

// Round 2
// 233.052 us; speedup vs baseline: 1.0659x; 1.0313x over previous
//
#include <hip/hip_runtime.h>
#include <hip/hip_bf16.h>

// SupplyChainGNN: 3-layer GCN, N=50000, E=800000, H=64.
// Round 13: weights via wave-uniform scalar loads (readfirstlane -> SMEM pipe),
// WT LDS tile removed. LDS = ybuf only (~17KB) -> 8 blocks/CU (was 4), doubling
// resident gather waves. Conv restructured to single k-pass: 64 ds_read_b32 +
// uniform W-row loads + 16 FMA/k, fully hidden under other blocks' gathers.
// Gather inner loop unchanged (R10 structure).

#define HDIM 64
#define PB 128          // blocks in hist/bin passes
#define NPB 256         // nodes per bucket
#define NPB_SHIFT 8

__device__ inline unsigned bfpack(float lo, float hi) {
    unsigned ul = __float_as_uint(lo), uh = __float_as_uint(hi);
    ul += 0x7fffu + ((ul >> 16) & 1u);
    uh += 0x7fffu + ((uh >> 16) & 1u);
    return (ul >> 16) | (uh & 0xffff0000u);
}

__device__ inline float2 bfunpack(unsigned u) {
    float2 r;
    r.x = __uint_as_float(u << 16);
    r.y = __uint_as_float(u & 0xffff0000u);
    return r;
}

// Pass 1: histT[k*PB + p] = #edges of block p with dst in bucket k  (NB<=256)
__global__ __launch_bounds__(256) void hist_pass(const int* __restrict__ dst,
                                                 unsigned* __restrict__ histT,
                                                 int E, int NB) {
    __shared__ unsigned h[256];
    int t = threadIdx.x, p = blockIdx.x;
    h[t] = 0u;
    __syncthreads();
    int chunk = (E + PB - 1) / PB;
    int lo = p * chunk, hi = min(lo + chunk, E);
    for (int e = lo + t; e < hi; e += 256)
        atomicAdd(&h[dst[e] >> NPB_SHIFT], 1u);
    __syncthreads();
    if (t < NB) histT[t * PB + p] = h[t];
}

// Pass 2: per-bucket exclusive scan of its PB per-block counts (in place);
// bucket total -> btot[k].
__global__ __launch_bounds__(128) void scan_bucket(unsigned* __restrict__ histT,
                                                   unsigned* __restrict__ btot) {
    __shared__ unsigned s[PB];
    int t = threadIdx.x, k = blockIdx.x;
    unsigned v = histT[k * PB + t];
    s[t] = v;
    __syncthreads();
#pragma unroll
    for (int off = 1; off < PB; off <<= 1) {
        unsigned u = (t >= off) ? s[t - off] : 0u;
        __syncthreads();
        s[t] += u;
        __syncthreads();
    }
    histT[k * PB + t] = s[t] - v;
    if (t == PB - 1) btot[k] = s[t];
}

// Pass 3: scatter packed (dst_local<<16)|src into bucket-grouped ebuf.
__global__ __launch_bounds__(256) void bin_pass(const int* __restrict__ ei,
                                                const unsigned* __restrict__ histT,
                                                const unsigned* __restrict__ btot,
                                                unsigned* __restrict__ ebuf,
                                                int E, int NB) {
    __shared__ unsigned bb[256];
    __shared__ unsigned cur[256];
    int t = threadIdx.x, p = blockIdx.x;
    unsigned bv = (t < NB) ? btot[t] : 0u;
    bb[t] = bv;
    __syncthreads();
#pragma unroll
    for (int off = 1; off < 256; off <<= 1) {
        unsigned u = (t >= off) ? bb[t - off] : 0u;
        __syncthreads();
        bb[t] += u;
        __syncthreads();
    }
    if (t < NB) cur[t] = histT[t * PB + p] + (bb[t] - bv);
    __syncthreads();
    int chunk = (E + PB - 1) / PB;
    int lo = p * chunk, hi = min(lo + chunk, E);
    for (int e = lo + t; e < hi; e += 256) {
        unsigned sN = (unsigned)ei[e];
        unsigned dN = (unsigned)ei[E + e];
        unsigned pos = atomicAdd(&cur[dN >> NPB_SHIFT], 1u);
        ebuf[pos] = ((dN & (NPB - 1u)) << 16) | sN;
    }
}

// Pass 4: one block per bucket -> row_ptr, dinv, csr_src.
__global__ __launch_bounds__(256) void csr_pass(const unsigned* __restrict__ ebuf,
                                                const unsigned* __restrict__ btot,
                                                unsigned* __restrict__ row_ptr,
                                                float* __restrict__ dinv,
                                                int* __restrict__ csr_src,
                                                int N, int E, int NB) {
    __shared__ unsigned bb[256];
    __shared__ unsigned cntL[NPB];
    __shared__ unsigned sc[NPB];
    __shared__ unsigned cur[NPB];
    int t = threadIdx.x, k = blockIdx.x;
    unsigned bv = (t < NB) ? btot[t] : 0u;
    bb[t] = bv;
    __syncthreads();
#pragma unroll
    for (int off = 1; off < 256; off <<= 1) {
        unsigned u = (t >= off) ? bb[t - off] : 0u;
        __syncthreads();
        bb[t] += u;
        __syncthreads();
    }
    unsigned e1 = bb[k];
    unsigned e0 = e1 - btot[k];
    int nbase = k << NPB_SHIFT;
    cntL[t] = 0u;
    __syncthreads();
    for (unsigned e = e0 + t; e < e1; e += 256)
        atomicAdd(&cntL[ebuf[e] >> 16], 1u);
    __syncthreads();
    unsigned v = cntL[t];
    sc[t] = v;
    __syncthreads();
#pragma unroll
    for (int off = 1; off < NPB; off <<= 1) {
        unsigned u = (t >= off) ? sc[t - off] : 0u;
        __syncthreads();
        sc[t] += u;
        __syncthreads();
    }
    unsigned pos0 = e0 + sc[t] - v;
    cur[t] = pos0;
    int node = nbase + t;
    if (node < N) {
        row_ptr[node] = pos0;
        dinv[node] = rsqrtf((float)(v + 1u));
    }
    if (k == NB - 1 && t == 0) row_ptr[N] = (unsigned)E;
    __syncthreads();
    for (unsigned e = e0 + t; e < e1; e += 256) {
        unsigned ed = ebuf[e];
        unsigned pos = atomicAdd(&cur[ed >> 16], 1u);
        csr_src[pos] = (int)(ed & 0xffffu);
    }
}

// hn[i] = bf16( dinv[i] * relu(x@W+b) ); thread per feature-pair.
__global__ __launch_bounds__(256) void encoder(const float* __restrict__ x,
                                               const float* __restrict__ W,
                                               const float* __restrict__ b,
                                               const float* __restrict__ dinv,
                                               unsigned* __restrict__ hn, int N) {
    int t = blockIdx.x * 256 + threadIdx.x;
    int i = t >> 5, jp = t & 31;
    if (i >= N) return;
    int j0 = 2 * jp;
    float a0 = b[j0], a1 = b[j0 + 1];
#pragma unroll
    for (int k = 0; k < 5; k++) {
        float xv = x[i * 5 + k];
        a0 = fmaf(xv, W[k * 64 + j0], a0);
        a1 = fmaf(xv, W[k * 64 + j0 + 1], a1);
    }
    float di = dinv[i];
    hn[t] = bfpack(di * fmaxf(a0, 0.0f), di * fmaxf(a1, 0.0f));
}

// Per-node gather (half-wave, 32 lanes, lane fl owns features 2fl,2fl+1).
// Software-pipelined 8-deep — unchanged from R10 (at scattered-request ceiling).
__device__ inline float2 gather_row(const unsigned* __restrict__ row_ptr,
                                    const int* __restrict__ csr_src,
                                    const unsigned* __restrict__ hn,
                                    int i, int fl) {
    float2 a0 = bfunpack(hn[(size_t)i * 32 + fl]);  // self term
    float2 a1 = {0.f, 0.f}, a2 = {0.f, 0.f}, a3 = {0.f, 0.f};
    float2 a4 = {0.f, 0.f}, a5 = {0.f, 0.f}, a6 = {0.f, 0.f}, a7 = {0.f, 0.f};
    unsigned e0 = row_ptr[i];
    unsigned cnt = row_ptr[i + 1] - e0;
    const int* idx = csr_src + e0;
    unsigned u = 0;
    if (cnt >= 8) {
        int s0 = idx[0], s1 = idx[1], s2 = idx[2], s3 = idx[3];
        int s4 = idx[4], s5 = idx[5], s6 = idx[6], s7 = idx[7];
        while (true) {
            unsigned v0 = hn[(size_t)s0 * 32 + fl];
            unsigned v1 = hn[(size_t)s1 * 32 + fl];
            unsigned v2 = hn[(size_t)s2 * 32 + fl];
            unsigned v3 = hn[(size_t)s3 * 32 + fl];
            unsigned v4 = hn[(size_t)s4 * 32 + fl];
            unsigned v5 = hn[(size_t)s5 * 32 + fl];
            unsigned v6 = hn[(size_t)s6 * 32 + fl];
            unsigned v7 = hn[(size_t)s7 * 32 + fl];
            unsigned un = u + 8;
            bool more = (un + 8 <= cnt);
            if (more) {
                s0 = idx[un + 0]; s1 = idx[un + 1]; s2 = idx[un + 2]; s3 = idx[un + 3];
                s4 = idx[un + 4]; s5 = idx[un + 5]; s6 = idx[un + 6]; s7 = idx[un + 7];
            }
            float2 f0 = bfunpack(v0), f1 = bfunpack(v1), f2 = bfunpack(v2), f3 = bfunpack(v3);
            float2 f4 = bfunpack(v4), f5 = bfunpack(v5), f6 = bfunpack(v6), f7 = bfunpack(v7);
            a0.x += f0.x; a0.y += f0.y;  a1.x += f1.x; a1.y += f1.y;
            a2.x += f2.x; a2.y += f2.y;  a3.x += f3.x; a3.y += f3.y;
            a4.x += f4.x; a4.y += f4.y;  a5.x += f5.x; a5.y += f5.y;
            a6.x += f6.x; a6.y += f6.y;  a7.x += f7.x; a7.y += f7.y;
            u = un;
            if (!more) break;
        }
    }
    if (u < cnt) {  // predicated parallel remainder (1..7 edges)
        unsigned last = cnt - 1;
        int s0 = idx[u];
        int s1 = idx[min(u + 1, last)];
        int s2 = idx[min(u + 2, last)];
        int s3 = idx[min(u + 3, last)];
        int s4 = idx[min(u + 4, last)];
        int s5 = idx[min(u + 5, last)];
        int s6 = idx[min(u + 6, last)];
        int s7 = idx[min(u + 7, last)];
        unsigned v0 = hn[(size_t)s0 * 32 + fl];
        unsigned v1 = hn[(size_t)s1 * 32 + fl];
        unsigned v2 = hn[(size_t)s2 * 32 + fl];
        unsigned v3 = hn[(size_t)s3 * 32 + fl];
        unsigned v4 = hn[(size_t)s4 * 32 + fl];
        unsigned v5 = hn[(size_t)s5 * 32 + fl];
        unsigned v6 = hn[(size_t)s6 * 32 + fl];
        unsigned v7 = hn[(size_t)s7 * 32 + fl];
        float2 f0 = bfunpack(v0), f1 = bfunpack(v1), f2 = bfunpack(v2), f3 = bfunpack(v3);
        float2 f4 = bfunpack(v4), f5 = bfunpack(v5), f6 = bfunpack(v6), f7 = bfunpack(v7);
        a0.x += f0.x;                        a0.y += f0.y;
        a1.x += (u + 1 < cnt) ? f1.x : 0.f;  a1.y += (u + 1 < cnt) ? f1.y : 0.f;
        a2.x += (u + 2 < cnt) ? f2.x : 0.f;  a2.y += (u + 2 < cnt) ? f2.y : 0.f;
        a3.x += (u + 3 < cnt) ? f3.x : 0.f;  a3.y += (u + 3 < cnt) ? f3.y : 0.f;
        a4.x += (u + 4 < cnt) ? f4.x : 0.f;  a4.y += (u + 4 < cnt) ? f4.y : 0.f;
        a5.x += (u + 5 < cnt) ? f5.x : 0.f;  a5.y += (u + 5 < cnt) ? f5.y : 0.f;
        a6.x += (u + 6 < cnt) ? f6.x : 0.f;  a6.y += (u + 6 < cnt) ? f6.y : 0.f;
        a7.x += (u + 7 < cnt) ? f7.x : 0.f;  a7.y += (u + 7 < cnt) ? f7.y : 0.f;
    }
    a0.x += a1.x; a0.y += a1.y;  a2.x += a3.x; a2.y += a3.y;
    a4.x += a5.x; a4.y += a5.y;  a6.x += a7.x; a6.y += a7.y;
    a0.x += a2.x; a0.y += a2.y;  a4.x += a6.x; a4.y += a6.y;
    a0.x += a4.x; a0.y += a4.y;
    return a0;
}

// 16 FMAs: acc0..acc3 (float4) += hk * W row segment (4x float4, wave-uniform)
#define CONV_K(WROW, HK) do {                                                   \
    float4 wa = ((const float4*)(WROW))[0];                                     \
    float4 wb = ((const float4*)(WROW))[1];                                     \
    float4 wc = ((const float4*)(WROW))[2];                                     \
    float4 wd = ((const float4*)(WROW))[3];                                     \
    acc0.x = fmaf(HK, wa.x, acc0.x); acc0.y = fmaf(HK, wa.y, acc0.y);           \
    acc0.z = fmaf(HK, wa.z, acc0.z); acc0.w = fmaf(HK, wa.w, acc0.w);           \
    acc1.x = fmaf(HK, wb.x, acc1.x); acc1.y = fmaf(HK, wb.y, acc1.y);           \
    acc1.z = fmaf(HK, wb.z, acc1.z); acc1.w = fmaf(HK, wb.w, acc1.w);           \
    acc2.x = fmaf(HK, wc.x, acc2.x); acc2.y = fmaf(HK, wc.y, acc2.y);           \
    acc2.z = fmaf(HK, wc.z, acc2.z); acc2.w = fmaf(HK, wc.w, acc2.w);           \
    acc3.x = fmaf(HK, wd.x, acc3.x); acc3.y = fmaf(HK, wd.y, acc3.y);           \
    acc3.z = fmaf(HK, wd.z, acc3.z); acc3.w = fmaf(HK, wd.w, acc3.w);           \
} while (0)

// Fused gather+conv, 64 nodes/block, 8 blocks/CU. Gather: 8 half-waves x 8
// nodes serial, rows staged feature-major in LDS (stride 65). Conv: thread per
// (node n=tid&63, output group jb=(tid>>6)*16); W rows read via wave-uniform
// scalar loads (SMEM pipe — off the vector path the gather saturates).
__global__ __launch_bounds__(256, 8) void gconv(const unsigned* __restrict__ row_ptr,
                                                const int* __restrict__ csr_src,
                                                const unsigned* __restrict__ hn_in,
                                                const float* __restrict__ W,
                                                const float* __restrict__ b,
                                                const float* __restrict__ dinv,
                                                unsigned* __restrict__ hn_out, int N) {
    __shared__ float ybuf[64 * 65];   // [feature][node]
    int tid = threadIdx.x;
    int hw = tid >> 5, fl = tid & 31;
    int base = blockIdx.x * 64;
    for (int s = 0; s < 8; s++) {
        int n = hw * 8 + s;
        int i = base + n;
        if (i < N) {
            float2 a = gather_row(row_ptr, csr_src, hn_in, i, fl);
            ybuf[(2 * fl) * 65 + n] = a.x;
            ybuf[(2 * fl + 1) * 65 + n] = a.y;
        }
    }
    __syncthreads();
    int n = tid & 63;
    int qt = __builtin_amdgcn_readfirstlane(tid >> 6);   // wave-uniform
    int i = base + n;
    if (i >= N) return;
    int jb = qt * 16;
    float di = dinv[i];
    float4 acc0 = {0.f, 0.f, 0.f, 0.f}, acc1 = acc0, acc2 = acc0, acc3 = acc0;
    const float* Wj = W + jb;
#pragma unroll
    for (int k = 0; k < 64; k++) {
        float hk = ybuf[k * 65 + n];
        CONV_K(Wj + k * 64, hk);
    }
    const float* bj = b + jb;
    unsigned pk[8];
    {
        float4 y;
        y.x = fmaxf(fmaf(di, acc0.x, bj[0]), 0.f) * di;
        y.y = fmaxf(fmaf(di, acc0.y, bj[1]), 0.f) * di;
        y.z = fmaxf(fmaf(di, acc0.z, bj[2]), 0.f) * di;
        y.w = fmaxf(fmaf(di, acc0.w, bj[3]), 0.f) * di;
        pk[0] = bfpack(y.x, y.y); pk[1] = bfpack(y.z, y.w);
        y.x = fmaxf(fmaf(di, acc1.x, bj[4]), 0.f) * di;
        y.y = fmaxf(fmaf(di, acc1.y, bj[5]), 0.f) * di;
        y.z = fmaxf(fmaf(di, acc1.z, bj[6]), 0.f) * di;
        y.w = fmaxf(fmaf(di, acc1.w, bj[7]), 0.f) * di;
        pk[2] = bfpack(y.x, y.y); pk[3] = bfpack(y.z, y.w);
        y.x = fmaxf(fmaf(di, acc2.x, bj[8]), 0.f) * di;
        y.y = fmaxf(fmaf(di, acc2.y, bj[9]), 0.f) * di;
        y.z = fmaxf(fmaf(di, acc2.z, bj[10]), 0.f) * di;
        y.w = fmaxf(fmaf(di, acc2.w, bj[11]), 0.f) * di;
        pk[4] = bfpack(y.x, y.y); pk[5] = bfpack(y.z, y.w);
        y.x = fmaxf(fmaf(di, acc3.x, bj[12]), 0.f) * di;
        y.y = fmaxf(fmaf(di, acc3.y, bj[13]), 0.f) * di;
        y.z = fmaxf(fmaf(di, acc3.z, bj[14]), 0.f) * di;
        y.w = fmaxf(fmaf(di, acc3.w, bj[15]), 0.f) * di;
        pk[6] = bfpack(y.x, y.y); pk[7] = bfpack(y.z, y.w);
    }
    uint4* dst = (uint4*)(hn_out + (size_t)i * 32 + qt * 8);
    dst[0] = make_uint4(pk[0], pk[1], pk[2], pk[3]);
    dst[1] = make_uint4(pk[4], pk[5], pk[6], pk[7]);
}

// Layer 2: fused gather + conv + both MLP heads -> out. Same scalar-load
// weight scheme for conv W, W_d1/W_i1, W_d2/W_i2.
__global__ __launch_bounds__(256, 8) void gconv_heads(const unsigned* __restrict__ row_ptr,
                                                      const int* __restrict__ csr_src,
                                                      const unsigned* __restrict__ hn_in,
                                                      const float* __restrict__ W,
                                                      const float* __restrict__ b,
                                                      const float* __restrict__ dinv,
                                                      const float* __restrict__ W_d1, const float* __restrict__ b_d1,
                                                      const float* __restrict__ W_d2, const float* __restrict__ b_d2,
                                                      const float* __restrict__ W_i1, const float* __restrict__ b_i1,
                                                      const float* __restrict__ W_i2, const float* __restrict__ b_i2,
                                                      float* __restrict__ out, int N) {
    __shared__ float ybuf[64 * 65];   // gathered rows, later y rows (feature-major)
    __shared__ float opart[256];
    int tid = threadIdx.x;
    int hw = tid >> 5, fl = tid & 31;
    int base = blockIdx.x * 64;
    for (int s = 0; s < 8; s++) {
        int n = hw * 8 + s;
        int i = base + n;
        if (i < N) {
            float2 a = gather_row(row_ptr, csr_src, hn_in, i, fl);
            ybuf[(2 * fl) * 65 + n] = a.x;
            ybuf[(2 * fl + 1) * 65 + n] = a.y;
        }
    }
    __syncthreads();
    int n = tid & 63;
    int qt = __builtin_amdgcn_readfirstlane(tid >> 6);   // wave-uniform
    int i = base + n;
    int jb = qt * 16;
    float y[16];
    if (i < N) {
        float di = dinv[i];
        float4 acc0 = {0.f, 0.f, 0.f, 0.f}, acc1 = acc0, acc2 = acc0, acc3 = acc0;
        const float* Wj = W + jb;
#pragma unroll
        for (int k = 0; k < 64; k++) {
            float hk = ybuf[k * 65 + n];
            CONV_K(Wj + k * 64, hk);
        }
        const float* bj = b + jb;
        y[0]  = fmaxf(fmaf(di, acc0.x, bj[0]),  0.f);
        y[1]  = fmaxf(fmaf(di, acc0.y, bj[1]),  0.f);
        y[2]  = fmaxf(fmaf(di, acc0.z, bj[2]),  0.f);
        y[3]  = fmaxf(fmaf(di, acc0.w, bj[3]),  0.f);
        y[4]  = fmaxf(fmaf(di, acc1.x, bj[4]),  0.f);
        y[5]  = fmaxf(fmaf(di, acc1.y, bj[5]),  0.f);
        y[6]  = fmaxf(fmaf(di, acc1.z, bj[6]),  0.f);
        y[7]  = fmaxf(fmaf(di, acc1.w, bj[7]),  0.f);
        y[8]  = fmaxf(fmaf(di, acc2.x, bj[8]),  0.f);
        y[9]  = fmaxf(fmaf(di, acc2.y, bj[9]),  0.f);
        y[10] = fmaxf(fmaf(di, acc2.z, bj[10]), 0.f);
        y[11] = fmaxf(fmaf(di, acc2.w, bj[11]), 0.f);
        y[12] = fmaxf(fmaf(di, acc3.x, bj[12]), 0.f);
        y[13] = fmaxf(fmaf(di, acc3.y, bj[13]), 0.f);
        y[14] = fmaxf(fmaf(di, acc3.z, bj[14]), 0.f);
        y[15] = fmaxf(fmaf(di, acc3.w, bj[15]), 0.f);
    }
    __syncthreads();   // all conv reads of ybuf done
    if (i < N) {
#pragma unroll
        for (int jj = 0; jj < 16; jj++) ybuf[(jb + jj) * 65 + n] = y[jj];
    }
    __syncthreads();
    int head = qt >> 1, jh = qt & 1;   // wave-uniform (derived from qt)
    int hb = jh * 16;
    float op = 0.f;
    if (i < N) {
        const float* W1 = (head ? W_i1 : W_d1) + hb;   // [64][32] row-major
        const float* b1 = (head ? b_i1 : b_d1) + hb;
        const float* W2 = (head ? W_i2 : W_d2) + hb;
        float4 acc0 = {0.f, 0.f, 0.f, 0.f}, acc1 = acc0, acc2 = acc0, acc3 = acc0;
#pragma unroll
        for (int k = 0; k < 64; k++) {
            float hk = ybuf[k * 65 + n];
            CONV_K(W1 + k * 32, hk);
        }
        op = fmaf(fmaxf(acc0.x + b1[0],  0.f), W2[0],  op);
        op = fmaf(fmaxf(acc0.y + b1[1],  0.f), W2[1],  op);
        op = fmaf(fmaxf(acc0.z + b1[2],  0.f), W2[2],  op);
        op = fmaf(fmaxf(acc0.w + b1[3],  0.f), W2[3],  op);
        op = fmaf(fmaxf(acc1.x + b1[4],  0.f), W2[4],  op);
        op = fmaf(fmaxf(acc1.y + b1[5],  0.f), W2[5],  op);
        op = fmaf(fmaxf(acc1.z + b1[6],  0.f), W2[6],  op);
        op = fmaf(fmaxf(acc1.w + b1[7],  0.f), W2[7],  op);
        op = fmaf(fmaxf(acc2.x + b1[8],  0.f), W2[8],  op);
        op = fmaf(fmaxf(acc2.y + b1[9],  0.f), W2[9],  op);
        op = fmaf(fmaxf(acc2.z + b1[10], 0.f), W2[10], op);
        op = fmaf(fmaxf(acc2.w + b1[11], 0.f), W2[11], op);
        op = fmaf(fmaxf(acc3.x + b1[12], 0.f), W2[12], op);
        op = fmaf(fmaxf(acc3.y + b1[13], 0.f), W2[13], op);
        op = fmaf(fmaxf(acc3.z + b1[14], 0.f), W2[14], op);
        op = fmaf(fmaxf(acc3.w + b1[15], 0.f), W2[15], op);
    }
    opart[(tid >> 6) * 64 + n] = op;   // note: use raw tid>>6 for the slot
    __syncthreads();
    if (tid < 128) {
        int n2 = tid & 63, hd = tid >> 6;
        int i2 = base + n2;
        if (i2 < N) {
            float o = opart[hd * 128 + n2] + opart[hd * 128 + 64 + n2]
                    + (hd ? b_i2[0] : b_d2[0]);
            out[(size_t)hd * N + i2] = o;
        }
    }
}

extern "C" void kernel_launch(void* const* d_in, const int* in_sizes, int n_in,
                              void* d_out, int out_size, void* d_ws, size_t ws_size,
                              hipStream_t stream) {
    const float* x      = (const float*)d_in[0];
    const int*   ei     = (const int*)d_in[1];
    const float* W_enc  = (const float*)d_in[2];
    const float* b_enc  = (const float*)d_in[3];
    const float* conv_W = (const float*)d_in[4];
    const float* conv_b = (const float*)d_in[5];
    const float* W_d1   = (const float*)d_in[6];
    const float* b_d1   = (const float*)d_in[7];
    const float* W_d2   = (const float*)d_in[8];
    const float* b_d2   = (const float*)d_in[9];
    const float* W_i1   = (const float*)d_in[10];
    const float* b_i1   = (const float*)d_in[11];
    const float* W_i2   = (const float*)d_in[12];
    const float* b_i2   = (const float*)d_in[13];

    const int N = in_sizes[0] / 5;
    const int E = in_sizes[1] / 2;
    const int NB = (N + NPB - 1) >> NPB_SHIFT;   // <= 256

    // Workspace layout (same as R12; hnA aliases ebuf — ebuf dead before encoder).
    float* g    = (float*)d_ws;                           // [N*64] region
    unsigned* hnA = (unsigned*)d_ws;                      // [N*32] bf16x2
    unsigned* hnB = (unsigned*)(g + (size_t)N * HDIM);    // [N*32] bf16x2
    float* dinv = (float*)(hnB + (size_t)N * 32);
    unsigned* row_ptr = (unsigned*)(dinv + N);            // [N+1]
    unsigned* histT   = row_ptr + N + 1;                  // [NB*PB]
    unsigned* btot    = histT + (size_t)NB * PB;          // [NB]
    int* csr_src      = (int*)(btot + NB);                // [E]
    unsigned* ebuf    = (unsigned*)d_ws;                  // [E] packed (dead before encoder)
    float* out = (float*)d_out;

    const int gBlocks = (N + 63) / 64;   // 64 nodes per fused block

    // CSR build: bucket sort, no global atomics
    hist_pass<<<PB, 256, 0, stream>>>(ei + E, histT, E, NB);
    scan_bucket<<<NB, 128, 0, stream>>>(histT, btot);
    bin_pass<<<PB, 256, 0, stream>>>(ei, histT, btot, ebuf, E, NB);
    csr_pass<<<NB, 256, 0, stream>>>(ebuf, btot, row_ptr, dinv, csr_src, N, E, NB);

    // encoder -> hnA (bf16, dinv-prescaled)
    encoder<<<(N * 32 + 255) / 256, 256, 0, stream>>>(x, W_enc, b_enc, dinv, hnA, N);

    // fused gather+conv per layer (ping-pong hnA/hnB), layer 2 fused with heads
    gconv<<<gBlocks, 256, 0, stream>>>(row_ptr, csr_src, hnA,
                                       conv_W + 0 * HDIM * HDIM, conv_b + 0 * HDIM,
                                       dinv, hnB, N);
    gconv<<<gBlocks, 256, 0, stream>>>(row_ptr, csr_src, hnB,
                                       conv_W + 1 * HDIM * HDIM, conv_b + 1 * HDIM,
                                       dinv, hnA, N);
    gconv_heads<<<gBlocks, 256, 0, stream>>>(row_ptr, csr_src, hnA,
                                             conv_W + 2 * HDIM * HDIM, conv_b + 2 * HDIM,
                                             dinv, W_d1, b_d1, W_d2, b_d2,
                                             W_i1, b_i1, W_i2, b_i2, out, N);
}

// Round 3
// 220.695 us; speedup vs baseline: 1.1256x; 1.0560x over previous
//
#include <hip/hip_runtime.h>
#include <hip/hip_bf16.h>

// SupplyChainGNN: 3-layer GCN, N=50000, E=800000, H=64.
// Round 14: 512-thread fused blocks (same 64-node tile). 16 half-waves x 4
// nodes serial (was 8 x 8) -> 2x resident gather half-waves per CU (grid was
// the occupancy cap at 3.05 blocks/CU, not LDS). Conv: thread per (node, 8
// outputs), qt = tid>>6 still wave-uniform -> scalar weight loads unchanged.
// Heads: thread per (head, 8-out group, node) + 4-way partial reduce in LDS.

#define HDIM 64
#define PB 128          // blocks in hist/bin passes
#define NPB 256         // nodes per bucket
#define NPB_SHIFT 8

__device__ inline unsigned bfpack(float lo, float hi) {
    unsigned ul = __float_as_uint(lo), uh = __float_as_uint(hi);
    ul += 0x7fffu + ((ul >> 16) & 1u);
    uh += 0x7fffu + ((uh >> 16) & 1u);
    return (ul >> 16) | (uh & 0xffff0000u);
}

__device__ inline float2 bfunpack(unsigned u) {
    float2 r;
    r.x = __uint_as_float(u << 16);
    r.y = __uint_as_float(u & 0xffff0000u);
    return r;
}

// Pass 1: histT[k*PB + p] = #edges of block p with dst in bucket k  (NB<=256)
__global__ __launch_bounds__(256) void hist_pass(const int* __restrict__ dst,
                                                 unsigned* __restrict__ histT,
                                                 int E, int NB) {
    __shared__ unsigned h[256];
    int t = threadIdx.x, p = blockIdx.x;
    h[t] = 0u;
    __syncthreads();
    int chunk = (E + PB - 1) / PB;
    int lo = p * chunk, hi = min(lo + chunk, E);
    for (int e = lo + t; e < hi; e += 256)
        atomicAdd(&h[dst[e] >> NPB_SHIFT], 1u);
    __syncthreads();
    if (t < NB) histT[t * PB + p] = h[t];
}

// Pass 2: per-bucket exclusive scan of its PB per-block counts (in place);
// bucket total -> btot[k].
__global__ __launch_bounds__(128) void scan_bucket(unsigned* __restrict__ histT,
                                                   unsigned* __restrict__ btot) {
    __shared__ unsigned s[PB];
    int t = threadIdx.x, k = blockIdx.x;
    unsigned v = histT[k * PB + t];
    s[t] = v;
    __syncthreads();
#pragma unroll
    for (int off = 1; off < PB; off <<= 1) {
        unsigned u = (t >= off) ? s[t - off] : 0u;
        __syncthreads();
        s[t] += u;
        __syncthreads();
    }
    histT[k * PB + t] = s[t] - v;
    if (t == PB - 1) btot[k] = s[t];
}

// Pass 3: scatter packed (dst_local<<16)|src into bucket-grouped ebuf.
__global__ __launch_bounds__(256) void bin_pass(const int* __restrict__ ei,
                                                const unsigned* __restrict__ histT,
                                                const unsigned* __restrict__ btot,
                                                unsigned* __restrict__ ebuf,
                                                int E, int NB) {
    __shared__ unsigned bb[256];
    __shared__ unsigned cur[256];
    int t = threadIdx.x, p = blockIdx.x;
    unsigned bv = (t < NB) ? btot[t] : 0u;
    bb[t] = bv;
    __syncthreads();
#pragma unroll
    for (int off = 1; off < 256; off <<= 1) {
        unsigned u = (t >= off) ? bb[t - off] : 0u;
        __syncthreads();
        bb[t] += u;
        __syncthreads();
    }
    if (t < NB) cur[t] = histT[t * PB + p] + (bb[t] - bv);
    __syncthreads();
    int chunk = (E + PB - 1) / PB;
    int lo = p * chunk, hi = min(lo + chunk, E);
    for (int e = lo + t; e < hi; e += 256) {
        unsigned sN = (unsigned)ei[e];
        unsigned dN = (unsigned)ei[E + e];
        unsigned pos = atomicAdd(&cur[dN >> NPB_SHIFT], 1u);
        ebuf[pos] = ((dN & (NPB - 1u)) << 16) | sN;
    }
}

// Pass 4: one block per bucket -> row_ptr, dinv, csr_src.
__global__ __launch_bounds__(256) void csr_pass(const unsigned* __restrict__ ebuf,
                                                const unsigned* __restrict__ btot,
                                                unsigned* __restrict__ row_ptr,
                                                float* __restrict__ dinv,
                                                int* __restrict__ csr_src,
                                                int N, int E, int NB) {
    __shared__ unsigned bb[256];
    __shared__ unsigned cntL[NPB];
    __shared__ unsigned sc[NPB];
    __shared__ unsigned cur[NPB];
    int t = threadIdx.x, k = blockIdx.x;
    unsigned bv = (t < NB) ? btot[t] : 0u;
    bb[t] = bv;
    __syncthreads();
#pragma unroll
    for (int off = 1; off < 256; off <<= 1) {
        unsigned u = (t >= off) ? bb[t - off] : 0u;
        __syncthreads();
        bb[t] += u;
        __syncthreads();
    }
    unsigned e1 = bb[k];
    unsigned e0 = e1 - btot[k];
    int nbase = k << NPB_SHIFT;
    cntL[t] = 0u;
    __syncthreads();
    for (unsigned e = e0 + t; e < e1; e += 256)
        atomicAdd(&cntL[ebuf[e] >> 16], 1u);
    __syncthreads();
    unsigned v = cntL[t];
    sc[t] = v;
    __syncthreads();
#pragma unroll
    for (int off = 1; off < NPB; off <<= 1) {
        unsigned u = (t >= off) ? sc[t - off] : 0u;
        __syncthreads();
        sc[t] += u;
        __syncthreads();
    }
    unsigned pos0 = e0 + sc[t] - v;
    cur[t] = pos0;
    int node = nbase + t;
    if (node < N) {
        row_ptr[node] = pos0;
        dinv[node] = rsqrtf((float)(v + 1u));
    }
    if (k == NB - 1 && t == 0) row_ptr[N] = (unsigned)E;
    __syncthreads();
    for (unsigned e = e0 + t; e < e1; e += 256) {
        unsigned ed = ebuf[e];
        unsigned pos = atomicAdd(&cur[ed >> 16], 1u);
        csr_src[pos] = (int)(ed & 0xffffu);
    }
}

// hn[i] = bf16( dinv[i] * relu(x@W+b) ); thread per feature-pair.
__global__ __launch_bounds__(256) void encoder(const float* __restrict__ x,
                                               const float* __restrict__ W,
                                               const float* __restrict__ b,
                                               const float* __restrict__ dinv,
                                               unsigned* __restrict__ hn, int N) {
    int t = blockIdx.x * 256 + threadIdx.x;
    int i = t >> 5, jp = t & 31;
    if (i >= N) return;
    int j0 = 2 * jp;
    float a0 = b[j0], a1 = b[j0 + 1];
#pragma unroll
    for (int k = 0; k < 5; k++) {
        float xv = x[i * 5 + k];
        a0 = fmaf(xv, W[k * 64 + j0], a0);
        a1 = fmaf(xv, W[k * 64 + j0 + 1], a1);
    }
    float di = dinv[i];
    hn[t] = bfpack(di * fmaxf(a0, 0.0f), di * fmaxf(a1, 0.0f));
}

// Per-node gather (half-wave, 32 lanes, lane fl owns features 2fl,2fl+1).
// Software-pipelined 8-deep — unchanged from R10 (structure at ceiling test).
__device__ inline float2 gather_row(const unsigned* __restrict__ row_ptr,
                                    const int* __restrict__ csr_src,
                                    const unsigned* __restrict__ hn,
                                    int i, int fl) {
    float2 a0 = bfunpack(hn[(size_t)i * 32 + fl]);  // self term
    float2 a1 = {0.f, 0.f}, a2 = {0.f, 0.f}, a3 = {0.f, 0.f};
    float2 a4 = {0.f, 0.f}, a5 = {0.f, 0.f}, a6 = {0.f, 0.f}, a7 = {0.f, 0.f};
    unsigned e0 = row_ptr[i];
    unsigned cnt = row_ptr[i + 1] - e0;
    const int* idx = csr_src + e0;
    unsigned u = 0;
    if (cnt >= 8) {
        int s0 = idx[0], s1 = idx[1], s2 = idx[2], s3 = idx[3];
        int s4 = idx[4], s5 = idx[5], s6 = idx[6], s7 = idx[7];
        while (true) {
            unsigned v0 = hn[(size_t)s0 * 32 + fl];
            unsigned v1 = hn[(size_t)s1 * 32 + fl];
            unsigned v2 = hn[(size_t)s2 * 32 + fl];
            unsigned v3 = hn[(size_t)s3 * 32 + fl];
            unsigned v4 = hn[(size_t)s4 * 32 + fl];
            unsigned v5 = hn[(size_t)s5 * 32 + fl];
            unsigned v6 = hn[(size_t)s6 * 32 + fl];
            unsigned v7 = hn[(size_t)s7 * 32 + fl];
            unsigned un = u + 8;
            bool more = (un + 8 <= cnt);
            if (more) {
                s0 = idx[un + 0]; s1 = idx[un + 1]; s2 = idx[un + 2]; s3 = idx[un + 3];
                s4 = idx[un + 4]; s5 = idx[un + 5]; s6 = idx[un + 6]; s7 = idx[un + 7];
            }
            float2 f0 = bfunpack(v0), f1 = bfunpack(v1), f2 = bfunpack(v2), f3 = bfunpack(v3);
            float2 f4 = bfunpack(v4), f5 = bfunpack(v5), f6 = bfunpack(v6), f7 = bfunpack(v7);
            a0.x += f0.x; a0.y += f0.y;  a1.x += f1.x; a1.y += f1.y;
            a2.x += f2.x; a2.y += f2.y;  a3.x += f3.x; a3.y += f3.y;
            a4.x += f4.x; a4.y += f4.y;  a5.x += f5.x; a5.y += f5.y;
            a6.x += f6.x; a6.y += f6.y;  a7.x += f7.x; a7.y += f7.y;
            u = un;
            if (!more) break;
        }
    }
    if (u < cnt) {  // predicated parallel remainder (1..7 edges)
        unsigned last = cnt - 1;
        int s0 = idx[u];
        int s1 = idx[min(u + 1, last)];
        int s2 = idx[min(u + 2, last)];
        int s3 = idx[min(u + 3, last)];
        int s4 = idx[min(u + 4, last)];
        int s5 = idx[min(u + 5, last)];
        int s6 = idx[min(u + 6, last)];
        int s7 = idx[min(u + 7, last)];
        unsigned v0 = hn[(size_t)s0 * 32 + fl];
        unsigned v1 = hn[(size_t)s1 * 32 + fl];
        unsigned v2 = hn[(size_t)s2 * 32 + fl];
        unsigned v3 = hn[(size_t)s3 * 32 + fl];
        unsigned v4 = hn[(size_t)s4 * 32 + fl];
        unsigned v5 = hn[(size_t)s5 * 32 + fl];
        unsigned v6 = hn[(size_t)s6 * 32 + fl];
        unsigned v7 = hn[(size_t)s7 * 32 + fl];
        float2 f0 = bfunpack(v0), f1 = bfunpack(v1), f2 = bfunpack(v2), f3 = bfunpack(v3);
        float2 f4 = bfunpack(v4), f5 = bfunpack(v5), f6 = bfunpack(v6), f7 = bfunpack(v7);
        a0.x += f0.x;                        a0.y += f0.y;
        a1.x += (u + 1 < cnt) ? f1.x : 0.f;  a1.y += (u + 1 < cnt) ? f1.y : 0.f;
        a2.x += (u + 2 < cnt) ? f2.x : 0.f;  a2.y += (u + 2 < cnt) ? f2.y : 0.f;
        a3.x += (u + 3 < cnt) ? f3.x : 0.f;  a3.y += (u + 3 < cnt) ? f3.y : 0.f;
        a4.x += (u + 4 < cnt) ? f4.x : 0.f;  a4.y += (u + 4 < cnt) ? f4.y : 0.f;
        a5.x += (u + 5 < cnt) ? f5.x : 0.f;  a5.y += (u + 5 < cnt) ? f5.y : 0.f;
        a6.x += (u + 6 < cnt) ? f6.x : 0.f;  a6.y += (u + 6 < cnt) ? f6.y : 0.f;
        a7.x += (u + 7 < cnt) ? f7.x : 0.f;  a7.y += (u + 7 < cnt) ? f7.y : 0.f;
    }
    a0.x += a1.x; a0.y += a1.y;  a2.x += a3.x; a2.y += a3.y;
    a4.x += a5.x; a4.y += a5.y;  a6.x += a7.x; a6.y += a7.y;
    a0.x += a2.x; a0.y += a2.y;  a4.x += a6.x; a4.y += a6.y;
    a0.x += a4.x; a0.y += a4.y;
    return a0;
}

// 8 FMAs: acc0,acc1 (float4) += hk * 8-wide W row segment (wave-uniform)
#define CONV_K8(WROW, HK) do {                                                  \
    float4 wa = ((const float4*)(WROW))[0];                                     \
    float4 wb = ((const float4*)(WROW))[1];                                     \
    acc0.x = fmaf(HK, wa.x, acc0.x); acc0.y = fmaf(HK, wa.y, acc0.y);           \
    acc0.z = fmaf(HK, wa.z, acc0.z); acc0.w = fmaf(HK, wa.w, acc0.w);           \
    acc1.x = fmaf(HK, wb.x, acc1.x); acc1.y = fmaf(HK, wb.y, acc1.y);           \
    acc1.z = fmaf(HK, wb.z, acc1.z); acc1.w = fmaf(HK, wb.w, acc1.w);           \
} while (0)

// Fused gather+conv, 64 nodes/block, 512 threads (16 half-waves x 4 nodes).
// Conv: thread per (node n=tid&63, 8 outputs jb=(tid>>6)*8); W rows via
// wave-uniform scalar loads.
__global__ __launch_bounds__(512, 6) void gconv(const unsigned* __restrict__ row_ptr,
                                                const int* __restrict__ csr_src,
                                                const unsigned* __restrict__ hn_in,
                                                const float* __restrict__ W,
                                                const float* __restrict__ b,
                                                const float* __restrict__ dinv,
                                                unsigned* __restrict__ hn_out, int N) {
    __shared__ float ybuf[64 * 65];   // [feature][node]
    int tid = threadIdx.x;
    int hw = tid >> 5, fl = tid & 31;
    int base = blockIdx.x * 64;
    for (int s = 0; s < 4; s++) {
        int n = hw * 4 + s;
        int i = base + n;
        if (i < N) {
            float2 a = gather_row(row_ptr, csr_src, hn_in, i, fl);
            ybuf[(2 * fl) * 65 + n] = a.x;
            ybuf[(2 * fl + 1) * 65 + n] = a.y;
        }
    }
    __syncthreads();
    int n = tid & 63;
    int qt = __builtin_amdgcn_readfirstlane(tid >> 6);   // 0..7, wave-uniform
    int i = base + n;
    if (i >= N) return;
    int jb = qt * 8;
    float di = dinv[i];
    float4 acc0 = {0.f, 0.f, 0.f, 0.f}, acc1 = acc0;
    const float* Wj = W + jb;
#pragma unroll
    for (int k = 0; k < 64; k++) {
        float hk = ybuf[k * 65 + n];
        CONV_K8(Wj + k * 64, hk);
    }
    const float* bj = b + jb;
    float4 y0, y1;
    y0.x = fmaxf(fmaf(di, acc0.x, bj[0]), 0.f) * di;
    y0.y = fmaxf(fmaf(di, acc0.y, bj[1]), 0.f) * di;
    y0.z = fmaxf(fmaf(di, acc0.z, bj[2]), 0.f) * di;
    y0.w = fmaxf(fmaf(di, acc0.w, bj[3]), 0.f) * di;
    y1.x = fmaxf(fmaf(di, acc1.x, bj[4]), 0.f) * di;
    y1.y = fmaxf(fmaf(di, acc1.y, bj[5]), 0.f) * di;
    y1.z = fmaxf(fmaf(di, acc1.z, bj[6]), 0.f) * di;
    y1.w = fmaxf(fmaf(di, acc1.w, bj[7]), 0.f) * di;
    uint4 p;
    p.x = bfpack(y0.x, y0.y);
    p.y = bfpack(y0.z, y0.w);
    p.z = bfpack(y1.x, y1.y);
    p.w = bfpack(y1.z, y1.w);
    *(uint4*)(hn_out + (size_t)i * 32 + qt * 4) = p;
}

// Layer 2: fused gather + conv + both MLP heads -> out (512 threads).
__global__ __launch_bounds__(512, 6) void gconv_heads(const unsigned* __restrict__ row_ptr,
                                                      const int* __restrict__ csr_src,
                                                      const unsigned* __restrict__ hn_in,
                                                      const float* __restrict__ W,
                                                      const float* __restrict__ b,
                                                      const float* __restrict__ dinv,
                                                      const float* __restrict__ W_d1, const float* __restrict__ b_d1,
                                                      const float* __restrict__ W_d2, const float* __restrict__ b_d2,
                                                      const float* __restrict__ W_i1, const float* __restrict__ b_i1,
                                                      const float* __restrict__ W_i2, const float* __restrict__ b_i2,
                                                      float* __restrict__ out, int N) {
    __shared__ float ybuf[64 * 65];   // gathered rows, later y rows (feature-major)
    __shared__ float opart[512];
    int tid = threadIdx.x;
    int hw = tid >> 5, fl = tid & 31;
    int base = blockIdx.x * 64;
    for (int s = 0; s < 4; s++) {
        int n = hw * 4 + s;
        int i = base + n;
        if (i < N) {
            float2 a = gather_row(row_ptr, csr_src, hn_in, i, fl);
            ybuf[(2 * fl) * 65 + n] = a.x;
            ybuf[(2 * fl + 1) * 65 + n] = a.y;
        }
    }
    __syncthreads();
    int n = tid & 63;
    int qt = __builtin_amdgcn_readfirstlane(tid >> 6);   // 0..7, wave-uniform
    int i = base + n;
    int jb = qt * 8;
    float y[8];
    if (i < N) {
        float di = dinv[i];
        float4 acc0 = {0.f, 0.f, 0.f, 0.f}, acc1 = acc0;
        const float* Wj = W + jb;
#pragma unroll
        for (int k = 0; k < 64; k++) {
            float hk = ybuf[k * 65 + n];
            CONV_K8(Wj + k * 64, hk);
        }
        const float* bj = b + jb;
        y[0] = fmaxf(fmaf(di, acc0.x, bj[0]), 0.f);
        y[1] = fmaxf(fmaf(di, acc0.y, bj[1]), 0.f);
        y[2] = fmaxf(fmaf(di, acc0.z, bj[2]), 0.f);
        y[3] = fmaxf(fmaf(di, acc0.w, bj[3]), 0.f);
        y[4] = fmaxf(fmaf(di, acc1.x, bj[4]), 0.f);
        y[5] = fmaxf(fmaf(di, acc1.y, bj[5]), 0.f);
        y[6] = fmaxf(fmaf(di, acc1.z, bj[6]), 0.f);
        y[7] = fmaxf(fmaf(di, acc1.w, bj[7]), 0.f);
    }
    __syncthreads();   // all conv reads of ybuf done
    if (i < N) {
#pragma unroll
        for (int jj = 0; jj < 8; jj++) ybuf[(jb + jj) * 65 + n] = y[jj];
    }
    __syncthreads();
    // heads: hd = tid>>8 (head), q2 = (tid>>6)&3 (8-out group), n = tid&63
    int hd = __builtin_amdgcn_readfirstlane(tid >> 8);        // 0/1, wave-uniform
    int q2 = __builtin_amdgcn_readfirstlane((tid >> 6) & 3);  // 0..3, wave-uniform
    int hb = q2 * 8;
    float op = 0.f;
    if (i < N) {
        const float* W1 = (hd ? W_i1 : W_d1) + hb;   // [64][32] row-major
        const float* b1 = (hd ? b_i1 : b_d1) + hb;
        const float* W2 = (hd ? W_i2 : W_d2) + hb;
        float4 acc0 = {0.f, 0.f, 0.f, 0.f}, acc1 = acc0;
#pragma unroll
        for (int k = 0; k < 64; k++) {
            float hk = ybuf[k * 65 + n];
            CONV_K8(W1 + k * 32, hk);
        }
        op = fmaf(fmaxf(acc0.x + b1[0], 0.f), W2[0], op);
        op = fmaf(fmaxf(acc0.y + b1[1], 0.f), W2[1], op);
        op = fmaf(fmaxf(acc0.z + b1[2], 0.f), W2[2], op);
        op = fmaf(fmaxf(acc0.w + b1[3], 0.f), W2[3], op);
        op = fmaf(fmaxf(acc1.x + b1[4], 0.f), W2[4], op);
        op = fmaf(fmaxf(acc1.y + b1[5], 0.f), W2[5], op);
        op = fmaf(fmaxf(acc1.z + b1[6], 0.f), W2[6], op);
        op = fmaf(fmaxf(acc1.w + b1[7], 0.f), W2[7], op);
    }
    opart[tid] = op;
    __syncthreads();
    if (tid < 128) {
        int n2 = tid & 63, h2 = tid >> 6;
        int i2 = base + n2;
        if (i2 < N) {
            int o0 = h2 * 256 + n2;
            float o = opart[o0] + opart[o0 + 64] + opart[o0 + 128] + opart[o0 + 192]
                    + (h2 ? b_i2[0] : b_d2[0]);
            out[(size_t)h2 * N + i2] = o;
        }
    }
}

extern "C" void kernel_launch(void* const* d_in, const int* in_sizes, int n_in,
                              void* d_out, int out_size, void* d_ws, size_t ws_size,
                              hipStream_t stream) {
    const float* x      = (const float*)d_in[0];
    const int*   ei     = (const int*)d_in[1];
    const float* W_enc  = (const float*)d_in[2];
    const float* b_enc  = (const float*)d_in[3];
    const float* conv_W = (const float*)d_in[4];
    const float* conv_b = (const float*)d_in[5];
    const float* W_d1   = (const float*)d_in[6];
    const float* b_d1   = (const float*)d_in[7];
    const float* W_d2   = (const float*)d_in[8];
    const float* b_d2   = (const float*)d_in[9];
    const float* W_i1   = (const float*)d_in[10];
    const float* b_i1   = (const float*)d_in[11];
    const float* W_i2   = (const float*)d_in[12];
    const float* b_i2   = (const float*)d_in[13];

    const int N = in_sizes[0] / 5;
    const int E = in_sizes[1] / 2;
    const int NB = (N + NPB - 1) >> NPB_SHIFT;   // <= 256

    // Workspace layout (same as R13; hnA aliases ebuf — ebuf dead before encoder).
    float* g    = (float*)d_ws;                           // [N*64] region
    unsigned* hnA = (unsigned*)d_ws;                      // [N*32] bf16x2
    unsigned* hnB = (unsigned*)(g + (size_t)N * HDIM);    // [N*32] bf16x2
    float* dinv = (float*)(hnB + (size_t)N * 32);
    unsigned* row_ptr = (unsigned*)(dinv + N);            // [N+1]
    unsigned* histT   = row_ptr + N + 1;                  // [NB*PB]
    unsigned* btot    = histT + (size_t)NB * PB;          // [NB]
    int* csr_src      = (int*)(btot + NB);                // [E]
    unsigned* ebuf    = (unsigned*)d_ws;                  // [E] packed (dead before encoder)
    float* out = (float*)d_out;

    const int gBlocks = (N + 63) / 64;   // 64 nodes per fused block

    // CSR build: bucket sort, no global atomics
    hist_pass<<<PB, 256, 0, stream>>>(ei + E, histT, E, NB);
    scan_bucket<<<NB, 128, 0, stream>>>(histT, btot);
    bin_pass<<<PB, 256, 0, stream>>>(ei, histT, btot, ebuf, E, NB);
    csr_pass<<<NB, 256, 0, stream>>>(ebuf, btot, row_ptr, dinv, csr_src, N, E, NB);

    // encoder -> hnA (bf16, dinv-prescaled)
    encoder<<<(N * 32 + 255) / 256, 256, 0, stream>>>(x, W_enc, b_enc, dinv, hnA, N);

    // fused gather+conv per layer (ping-pong hnA/hnB), layer 2 fused with heads
    gconv<<<gBlocks, 512, 0, stream>>>(row_ptr, csr_src, hnA,
                                       conv_W + 0 * HDIM * HDIM, conv_b + 0 * HDIM,
                                       dinv, hnB, N);
    gconv<<<gBlocks, 512, 0, stream>>>(row_ptr, csr_src, hnB,
                                       conv_W + 1 * HDIM * HDIM, conv_b + 1 * HDIM,
                                       dinv, hnA, N);
    gconv_heads<<<gBlocks, 512, 0, stream>>>(row_ptr, csr_src, hnA,
                                             conv_W + 2 * HDIM * HDIM, conv_b + 2 * HDIM,
                                             dinv, W_d1, b_d1, W_d2, b_d2,
                                             W_i1, b_i1, W_i2, b_i2, out, N);
}